// Round 3
// baseline (1811.076 us; speedup 1.0000x reference)
//
#include <hip/hip_runtime.h>
#include <cstddef>

#define WIDTH 768
#define NTOK 98      // FD*(L_TOK-1)
#define DH 392       // 4*98
#define KCL 49
#define NGRP 384     // B*AFTER_F
#define RT 16        // d-rows per MLP block

// ---------------- Kernel 1: token MLP -> centroids ----------------
// One block handles one n and a 16-wide slice of d (columns of data).
// Row vector v[t] = data[n,t,d] = x[1+l, b*12+a*2+f, d], t=f*49+l.
__global__ __launch_bounds__(256) void k_mlp(
    const float* __restrict__ x,
    const float* __restrict__ w1, const float* __restrict__ b1,
    const float* __restrict__ g1, const float* __restrict__ be1,
    const float* __restrict__ w2, const float* __restrict__ b2,
    const float* __restrict__ g2, const float* __restrict__ be2,
    const float* __restrict__ w3, const float* __restrict__ b3,
    const float* __restrict__ g3, const float* __restrict__ be3,
    float* __restrict__ cent)
{
    __shared__ float sv[NTOK * RT];        // v[t][r]
    __shared__ float sh1[DH * RT];         // h1[j][r]
    __shared__ float sh2[NTOK * RT];       // h2[o][r]
    __shared__ float sh3[KCL * (RT + 1)];  // h3[c][r], padded stride 17
    __shared__ float smu[RT], srs[RT];

    const int tid = threadIdx.x;
    const int bid = blockIdx.x;
    const int n  = bid / (WIDTH / RT);
    const int dt = bid % (WIDTH / RT);
    const int d0 = dt * RT;
    const int a = n >> 6, b = n & 63;
    const int bt0 = b * 12 + a * 2;

    // ---- load v tile ----
    for (int i = tid; i < NTOK * RT; i += 256) {
        int t = i >> 4, r = i & 15;
        int f = t / KCL, l = t - f * KCL;
        sv[i] = x[((size_t)(1 + l) * WIDTH + bt0 + f) * WIDTH + d0 + r];
    }
    __syncthreads();

    // ---- GEMM1: h1[j][r] = sum_t v[t][r]*W1[t][j], tile 4j x 8r ----
    if (tid < 196) {
        int jt = tid % 98, rt = tid / 98;
        int j0 = jt * 4, r0 = rt * 8;
        float acc[4][8];
        #pragma unroll
        for (int jj = 0; jj < 4; jj++)
            #pragma unroll
            for (int rr = 0; rr < 8; rr++) acc[jj][rr] = 0.f;
        for (int t = 0; t < NTOK; t++) {
            float4 w = *(const float4*)(w1 + t * DH + j0);
            float4 va = *(const float4*)(sv + t * RT + r0);
            float4 vb = *(const float4*)(sv + t * RT + r0 + 4);
            float vv[8] = {va.x, va.y, va.z, va.w, vb.x, vb.y, vb.z, vb.w};
            float ww[4] = {w.x, w.y, w.z, w.w};
            #pragma unroll
            for (int jj = 0; jj < 4; jj++)
                #pragma unroll
                for (int rr = 0; rr < 8; rr++)
                    acc[jj][rr] = fmaf(ww[jj], vv[rr], acc[jj][rr]);
        }
        #pragma unroll
        for (int jj = 0; jj < 4; jj++) {
            float bb = b1[j0 + jj];
            #pragma unroll
            for (int rr = 0; rr < 8; rr++)
                sh1[(j0 + jj) * RT + r0 + rr] = acc[jj][rr] + bb;
        }
    }
    __syncthreads();

    // ---- LN1 over j (392) per row r ----
    {
        int r = tid >> 4, sub = tid & 15;
        float s = 0.f, ss = 0.f;
        for (int j = sub; j < DH; j += 16) { float h = sh1[j * RT + r]; s += h; ss += h * h; }
        #pragma unroll
        for (int o = 1; o < 16; o <<= 1) { s += __shfl_xor(s, o); ss += __shfl_xor(ss, o); }
        if (sub == 0) {
            float m = s * (1.f / DH);
            float var = ss * (1.f / DH) - m * m;
            smu[r] = m; srs[r] = rsqrtf(fmaxf(var, 0.f) + 1e-5f);
        }
    }
    __syncthreads();
    for (int i = tid; i < DH * RT; i += 256) {
        int j = i >> 4, r = i & 15;
        sh1[i] = (sh1[i] - smu[r]) * srs[r] * g1[j] + be1[j];
    }
    __syncthreads();

    // ---- GEMM2: h2[o][r] = sum_j h1[j][r]*W2[j][o], tile 2o x 4r ----
    if (tid < 196) {
        int ot = tid % 49, rt = tid / 49;
        int o0 = ot * 2, r0 = rt * 4;
        float acc[2][4];
        #pragma unroll
        for (int oo = 0; oo < 2; oo++)
            #pragma unroll
            for (int rr = 0; rr < 4; rr++) acc[oo][rr] = 0.f;
        for (int j = 0; j < DH; j++) {
            float2 w = *(const float2*)(w2 + j * NTOK + o0);
            float4 h = *(const float4*)(sh1 + j * RT + r0);
            float hv[4] = {h.x, h.y, h.z, h.w};
            #pragma unroll
            for (int rr = 0; rr < 4; rr++) {
                acc[0][rr] = fmaf(w.x, hv[rr], acc[0][rr]);
                acc[1][rr] = fmaf(w.y, hv[rr], acc[1][rr]);
            }
        }
        #pragma unroll
        for (int oo = 0; oo < 2; oo++) {
            float bb = b2[o0 + oo];
            #pragma unroll
            for (int rr = 0; rr < 4; rr++)
                sh2[(o0 + oo) * RT + r0 + rr] = acc[oo][rr] + bb;
        }
    }
    __syncthreads();

    // ---- LN2 over o (98) per row ----
    {
        int r = tid >> 4, sub = tid & 15;
        float s = 0.f, ss = 0.f;
        for (int o = sub; o < NTOK; o += 16) { float h = sh2[o * RT + r]; s += h; ss += h * h; }
        #pragma unroll
        for (int o = 1; o < 16; o <<= 1) { s += __shfl_xor(s, o); ss += __shfl_xor(ss, o); }
        if (sub == 0) {
            float m = s * (1.f / NTOK);
            float var = ss * (1.f / NTOK) - m * m;
            smu[r] = m; srs[r] = rsqrtf(fmaxf(var, 0.f) + 1e-5f);
        }
    }
    __syncthreads();
    for (int i = tid; i < NTOK * RT; i += 256) {
        int o = i >> 4, r = i & 15;
        sh2[i] = (sh2[i] - smu[r]) * srs[r] * g2[o] + be2[o];
    }
    __syncthreads();

    // ---- GEMM3: h3[c][r] = sum_j h2[j][r]*W3[j][c], tile 1c x 4r ----
    if (tid < 196) {
        int c = tid % 49, rt = tid / 49;
        int r0 = rt * 4;
        float acc[4] = {0.f, 0.f, 0.f, 0.f};
        for (int j = 0; j < NTOK; j++) {
            float w = w3[j * KCL + c];
            float4 h = *(const float4*)(sh2 + j * RT + r0);
            acc[0] = fmaf(w, h.x, acc[0]);
            acc[1] = fmaf(w, h.y, acc[1]);
            acc[2] = fmaf(w, h.z, acc[2]);
            acc[3] = fmaf(w, h.w, acc[3]);
        }
        float bb = b3[c];
        #pragma unroll
        for (int rr = 0; rr < 4; rr++)
            sh3[c * (RT + 1) + r0 + rr] = acc[rr] + bb;
    }
    __syncthreads();

    // ---- LN3 over c (49) per row ----
    {
        int r = tid >> 4, sub = tid & 15;
        float s = 0.f, ss = 0.f;
        for (int c = sub; c < KCL; c += 16) { float h = sh3[c * (RT + 1) + r]; s += h; ss += h * h; }
        #pragma unroll
        for (int o = 1; o < 16; o <<= 1) { s += __shfl_xor(s, o); ss += __shfl_xor(ss, o); }
        if (sub == 0) {
            float m = s * (1.f / KCL);
            float var = ss * (1.f / KCL) - m * m;
            smu[r] = m; srs[r] = rsqrtf(fmaxf(var, 0.f) + 1e-5f);
        }
    }
    __syncthreads();
    // normalize + write centroids: cent[n][k][d]
    for (int i = tid; i < KCL * RT; i += 256) {
        int c = i >> 4, r = i & 15;
        float val = (sh3[c * (RT + 1) + r] - smu[r]) * srs[r] * g3[c] + be3[c];
        cent[((size_t)n * KCL + c) * WIDTH + d0 + r] = val;
    }
}

// ---------------- Kernel 2: distances, min/argmin ----------------
// One wave handles (n, 4 consecutive tokens). Lane-parallel over d (768 = 12*64).
__global__ __launch_bounds__(256) void k_dist(
    const float* __restrict__ x, const float* __restrict__ cent,
    float* __restrict__ mind, int* __restrict__ assignp)
{
    int wid = blockIdx.x * 4 + (threadIdx.x >> 6);
    int lane = threadIdx.x & 63;
    int n = wid / 25, g = wid - n * 25;
    int t0 = g * 4;
    int a = n >> 6, b = n & 63;
    int bt0 = b * 12 + a * 2;

    float d[4][12];
    #pragma unroll
    for (int tt = 0; tt < 4; tt++) {
        int t = t0 + tt;
        bool valid = t < NTOK;
        int te = valid ? t : 0;
        int f = te / KCL, l = te - f * KCL;
        const float* src = x + ((size_t)(1 + l) * WIDTH + bt0 + f) * WIDTH + lane;
        #pragma unroll
        for (int i = 0; i < 12; i++) d[tt][i] = valid ? src[i * 64] : 0.f;
    }
    float nd[4];
    #pragma unroll
    for (int tt = 0; tt < 4; tt++) {
        float s = 0.f;
        #pragma unroll
        for (int i = 0; i < 12; i++) s = fmaf(d[tt][i], d[tt][i], s);
        #pragma unroll
        for (int o = 32; o > 0; o >>= 1) s += __shfl_xor(s, o);
        nd[tt] = s;
    }

    float minv[4] = {1e30f, 1e30f, 1e30f, 1e30f};
    int mini[4] = {0, 0, 0, 0};
    for (int k = 0; k < KCL; k++) {
        const float* cr = cent + ((size_t)n * KCL + k) * WIDTH + lane;
        float c[12];
        #pragma unroll
        for (int i = 0; i < 12; i++) c[i] = cr[i * 64];
        float cn = 0.f;
        #pragma unroll
        for (int i = 0; i < 12; i++) cn = fmaf(c[i], c[i], cn);
        float dot[4] = {0.f, 0.f, 0.f, 0.f};
        #pragma unroll
        for (int tt = 0; tt < 4; tt++)
            #pragma unroll
            for (int i = 0; i < 12; i++) dot[tt] = fmaf(d[tt][i], c[i], dot[tt]);
        #pragma unroll
        for (int o = 32; o > 0; o >>= 1) {
            cn += __shfl_xor(cn, o);
            #pragma unroll
            for (int tt = 0; tt < 4; tt++) dot[tt] += __shfl_xor(dot[tt], o);
        }
        #pragma unroll
        for (int tt = 0; tt < 4; tt++) {
            float dist = sqrtf(fmaxf(nd[tt] + cn - 2.f * dot[tt], 0.f));
            if (dist < minv[tt]) { minv[tt] = dist; mini[tt] = k; }  // first-min wins
        }
    }
    if (lane == 0) {
        int nt = NTOK - t0; if (nt > 4) nt = 4;
        for (int tt = 0; tt < nt; tt++) {
            mind[n * NTOK + t0 + tt] = minv[tt];
            assignp[n * NTOK + t0 + tt] = mini[tt];
        }
    }
}

// ---------------- Kernel 3: medoids, sort, gather, class token ----------------
__global__ __launch_bounds__(256) void k_medoid(
    const float* __restrict__ x, const float* __restrict__ mind,
    const int* __restrict__ assignp, float* __restrict__ out)
{
    __shared__ float smind[NTOK];
    __shared__ int sassign[NTOK];
    __shared__ int med[KCL], sorted[KCL];

    int n = blockIdx.x, tid = threadIdx.x;
    int a = n >> 6, b = n & 63;
    int np = b * 6 + a;          // output group ordering (B-major)
    int bt0 = b * 12 + a * 2;

    if (tid < NTOK) { smind[tid] = mind[n * NTOK + tid]; sassign[tid] = assignp[n * NTOK + tid]; }
    __syncthreads();

    if (tid < KCL) {
        float best = 1e30f; int bi = 0;   // empty cluster -> 0 (matches argmin of zeros)
        for (int t = 0; t < NTOK; t++)
            if (sassign[t] == tid && smind[t] < best) { best = smind[t]; bi = t; }
        med[tid] = bi;
    }
    __syncthreads();
    if (tid < KCL) {  // stable rank sort ascending
        int mk = med[tid], rank = 0;
        for (int j = 0; j < KCL; j++) {
            int mj = med[j];
            rank += (mj < mk) || (mj == mk && j < tid);
        }
        sorted[rank] = mk;
    }
    __syncthreads();

    // class token: mean of the two frames
    for (int dd = tid; dd < WIDTH; dd += 256)
        out[(size_t)np * WIDTH + dd] =
            0.5f * (x[(size_t)bt0 * WIDTH + dd] + x[(size_t)(bt0 + 1) * WIDTH + dd]);

    // gather medoid rows straight from x
    for (int k = 0; k < KCL; k++) {
        int m = sorted[k];
        int f = m / KCL, l = m - f * KCL;
        const float* src = x + ((size_t)(1 + l) * WIDTH + bt0 + f) * WIDTH;
        float* dst = out + ((size_t)(1 + k) * NGRP + np) * WIDTH;
        for (int dd = tid; dd < WIDTH; dd += 256) dst[dd] = src[dd];
    }
}

// ---------------- Kernel 4: loss reduction ----------------
__global__ __launch_bounds__(256) void k_loss(const float* __restrict__ mind,
                                              float* __restrict__ out_loss)
{
    __shared__ float red[256];
    float s = 0.f;
    for (int i = threadIdx.x; i < NGRP * NTOK; i += 256) s += mind[i];
    red[threadIdx.x] = s;
    __syncthreads();
    for (int o = 128; o > 0; o >>= 1) {
        if (threadIdx.x < o) red[threadIdx.x] += red[threadIdx.x + o];
        __syncthreads();
    }
    if (threadIdx.x == 0) out_loss[0] = red[0] * (1.f / NGRP);
}

extern "C" void kernel_launch(void* const* d_in, const int* in_sizes, int n_in,
                              void* d_out, int out_size, void* d_ws, size_t ws_size,
                              hipStream_t stream)
{
    const float* x   = (const float*)d_in[0];
    const float* w1  = (const float*)d_in[1];
    const float* b1  = (const float*)d_in[2];
    const float* g1  = (const float*)d_in[3];
    const float* be1 = (const float*)d_in[4];
    const float* w2  = (const float*)d_in[5];
    const float* b2  = (const float*)d_in[6];
    const float* g2  = (const float*)d_in[7];
    const float* be2 = (const float*)d_in[8];
    const float* w3  = (const float*)d_in[9];
    const float* b3  = (const float*)d_in[10];
    const float* g3  = (const float*)d_in[11];
    const float* be3 = (const float*)d_in[12];
    float* out = (float*)d_out;

    float* cent = (float*)d_ws;                                  // 384*49*768 f32
    float* mind = cent + (size_t)NGRP * KCL * WIDTH;             // 37632 f32
    int* assignp = (int*)(mind + NGRP * NTOK);                   // 37632 i32

    k_mlp<<<NGRP * (WIDTH / RT), 256, 0, stream>>>(x, w1, b1, g1, be1,
                                                   w2, b2, g2, be2,
                                                   w3, b3, g3, be3, cent);
    k_dist<<<(NGRP * 25) / 4, 256, 0, stream>>>(x, cent, mind, assignp);
    k_medoid<<<NGRP, 256, 0, stream>>>(x, mind, assignp, out);
    k_loss<<<1, 256, 0, stream>>>(mind, out + (out_size - 1));
}

// Round 4
// 859.781 us; speedup vs baseline: 2.1064x; 2.1064x over previous
//
#include <hip/hip_runtime.h>
#include <cstddef>

#define WIDTH 768
#define NTOK 98      // FD*(L_TOK-1)
#define DH 392       // 4*98
#define KCL 49
#define NGRP 384     // B*AFTER_F

typedef unsigned short ushort_t;
typedef unsigned int uint_t;
typedef __attribute__((ext_vector_type(4))) float f32x4;
typedef __attribute__((ext_vector_type(8))) short bf16x8;

static __device__ __forceinline__ ushort_t f2bf(float f) {
    union { float f; uint_t u; } v; v.f = f;
    uint_t u = v.u;
    uint_t r = (u + 0x7FFFu + ((u >> 16) & 1u)) >> 16;
    return (ushort_t)r;
}
static __device__ __forceinline__ uint_t pack2(float a, float b) {
    return (uint_t)f2bf(a) | ((uint_t)f2bf(b) << 16);
}

// ---------------- Prep: transposed bf16 weights with LN-affine folding ----------------
// w1T[400][128]: w1T[j][t] = w1[t][j] (t<98), b1[j] (t==98), else 0; j>=392 rows zero.
// w2T[112][416]: w2T[o][j] = g1[j]*w2[j][o] (j<392), else 0; o>=98 rows zero.
// w3T[64][128]:  w3T[c][j] = g2[j]*w3[j][c] (j<98), bias3t[c] (j==98), else 0; c>=49 zero.
// bias2t[o] = sum_j be1[j]*w2[j][o] + b2[o]   (added in-register before LN2)
__global__ __launch_bounds__(256) void k_prep(
    const float* __restrict__ w1, const float* __restrict__ b1,
    const float* __restrict__ g1, const float* __restrict__ be1,
    const float* __restrict__ w2, const float* __restrict__ b2,
    const float* __restrict__ g2, const float* __restrict__ be2,
    const float* __restrict__ w3, const float* __restrict__ b3,
    ushort_t* __restrict__ w1T, ushort_t* __restrict__ w2T,
    ushort_t* __restrict__ w3T, float* __restrict__ bias2t)
{
    __shared__ float sb3[64];
    const int tid = threadIdx.x;
    if (blockIdx.x == 0) {
        if (tid < 98) {
            float s = b2[tid];
            for (int j = 0; j < DH; j++) s += be1[j] * w2[j * NTOK + tid];
            bias2t[tid] = s;
        }
        if (tid >= 128 && tid < 177) {
            int c = tid - 128;
            float s = b3[c];
            for (int j = 0; j < NTOK; j++) s += be2[j] * w3[j * KCL + c];
            sb3[c] = s;
        }
    }
    __syncthreads();
    if (blockIdx.x == 0 && tid < 64)
        w3T[tid * 128 + 98] = (tid < KCL) ? f2bf(sb3[tid]) : 0;

    // fills (grid-strided over 4 blocks x 256 threads)
    for (int i = blockIdx.x * 256 + tid; i < 400 * 128; i += 1024) {
        int j = i >> 7, k = i & 127;
        float v = 0.f;
        if (j < DH) {
            if (k < NTOK) v = w1[k * DH + j];
            else if (k == NTOK) v = b1[j];
        }
        w1T[i] = f2bf(v);
    }
    for (int i = blockIdx.x * 256 + tid; i < 112 * 416; i += 1024) {
        int o = i / 416, k = i - o * 416;
        float v = 0.f;
        if (o < NTOK && k < DH) v = g1[k] * w2[k * NTOK + o];
        w2T[i] = f2bf(v);
    }
    for (int i = blockIdx.x * 256 + tid; i < 64 * 128; i += 1024) {
        int c = i >> 7, k = i & 127;
        if (k == NTOK) continue;   // written by block 0 after bias3t
        float v = 0.f;
        if (c < KCL && k < NTOK) v = g2[k] * w3[k * KCL + c];
        w3T[i] = f2bf(v);
    }
}

// ---------------- Fused 3-layer token-MLP via bf16 MFMA ----------------
// grid = 384 n * 12 d-blocks; block = 256 (4 waves); wave w owns 16 d-rows.
// Orientation: D = A(Weights^T) x B(V^T): D[j][m], LN over j via 2-step butterfly.
__global__ __launch_bounds__(256, 2) void k_mlp(
    const float* __restrict__ x,
    const ushort_t* __restrict__ w1T, const ushort_t* __restrict__ w2T,
    const ushort_t* __restrict__ w3T, const float* __restrict__ bias2t,
    const float* __restrict__ g3, const float* __restrict__ be3,
    float* __restrict__ cent)
{
    __shared__ alignas(16) char smem[50176];   // sv [0,16384) overlapped by Hlds (4x12544)

    const int tid = threadIdx.x;
    const int wv = tid >> 6;          // wave 0..3
    const int l = tid & 63;
    const int g = l >> 4;             // lane quarter 0..3
    const int c16 = l & 15;

    const int n = blockIdx.x / 12;
    const int d0 = (blockIdx.x % 12) * 64;
    const int a = n >> 6, b = n & 63;
    const int bt0 = b * 12 + a * 2;

    // ---- stage V tile [64 d][13 k-octets] bf16, XOR-swizzled rows of 256B ----
    {
        const int m = tid & 63;              // lane = d index (coalesced)
        for (int oct = (tid >> 6); oct < 13; oct += 4) {
            ushort_t vals[8];
            #pragma unroll
            for (int e = 0; e < 8; e++) {
                int t = oct * 8 + e;
                float v;
                if (t < NTOK) {
                    int f = (t >= KCL), lt = t - f * KCL;
                    v = x[((size_t)(1 + lt) * WIDTH + bt0 + f) * WIDTH + d0 + m];
                } else v = (t == NTOK) ? 1.0f : 0.0f;
                vals[e] = f2bf(v);
            }
            uint4 u;
            u.x = (uint_t)vals[0] | ((uint_t)vals[1] << 16);
            u.y = (uint_t)vals[2] | ((uint_t)vals[3] << 16);
            u.z = (uint_t)vals[4] | ((uint_t)vals[5] << 16);
            u.w = (uint_t)vals[6] | ((uint_t)vals[7] << 16);
            *(uint4*)(smem + m * 256 + ((oct * 16) ^ ((m & 15) << 4))) = u;
        }
    }
    __syncthreads();

    // ---- B-frags (this wave's 16 d-rows), kept resident for GEMM1 ----
    bf16x8 bv[4];
    {
        const int mrow = wv * 16 + c16;
        #pragma unroll
        for (int ks = 0; ks < 4; ks++) {
            int oct = ks * 4 + g; if (oct > 12) oct = 12;   // k>=99 has A=0, value irrelevant
            bv[ks] = *(const bf16x8*)(smem + mrow * 256 + ((oct * 16) ^ ((mrow & 15) << 4)));
        }
    }
    __syncthreads();   // all waves done with sv; region reused as Hlds below

    char* hbase = smem + wv * 12544 + c16 * 784;   // this lane-column's H1 row (392 bf16)
    char* h2row = smem + wv * 12544 + c16 * 256;   // H2 row (128 bf16, XOR-swizzled)

    // ---- GEMM1: acc1[T][r] = H1[j = T*16 + g*4 + r][m = c16-col of this wave] ----
    f32x4 acc1[25];
    #pragma unroll
    for (int T = 0; T < 25; T++) acc1[T] = (f32x4){0.f, 0.f, 0.f, 0.f};
    #pragma unroll
    for (int ks = 0; ks < 4; ks++) {
        #pragma unroll
        for (int T = 0; T < 25; T++) {
            const bf16x8 av = *(const bf16x8*)(w1T + (T * 16 + c16) * 128 + (ks * 4 + g) * 8);
            acc1[T] = __builtin_amdgcn_mfma_f32_16x16x32_bf16(av, bv[ks], acc1[T], 0, 0, 0);
        }
    }

    // ---- LN1 (over j=392; padded rows are exactly zero, sums unguarded) ----
    {
        float S = 0.f, Q = 0.f;
        #pragma unroll
        for (int T = 0; T < 25; T++) {
            f32x4 v = acc1[T];
            S += v.x + v.y + v.z + v.w;
            Q += v.x * v.x + v.y * v.y + v.z * v.z + v.w * v.w;
        }
        S += __shfl_xor(S, 16); Q += __shfl_xor(Q, 16);
        S += __shfl_xor(S, 32); Q += __shfl_xor(Q, 32);
        float mu = S * (1.f / DH);
        float var = Q * (1.f / DH) - mu * mu;
        float rstd = rsqrtf(fmaxf(var, 0.f) + 1e-5f);
        #pragma unroll
        for (int T = 0; T < 25; T++) {
            if (T == 24 && g >= 2) continue;       // j>=392: outside row
            f32x4 v = acc1[T];
            uint2 u;
            u.x = pack2((v.x - mu) * rstd, (v.y - mu) * rstd);
            u.y = pack2((v.z - mu) * rstd, (v.w - mu) * rstd);
            *(uint2*)(hbase + (T * 16 + g * 4) * 2) = u;
        }
    }

    // ---- GEMM2: acc2[T2][r] = H2[o = T2*16 + g*4 + r][m] ----
    f32x4 acc2[7];
    #pragma unroll
    for (int T = 0; T < 7; T++) acc2[T] = (f32x4){0.f, 0.f, 0.f, 0.f};
    #pragma unroll
    for (int ks = 0; ks < 13; ks++) {
        int oct = ks * 4 + g; if (oct > 48) oct = 48;   // k>=392 has A=0
        const bf16x8 bvv = *(const bf16x8*)(hbase + oct * 16);
        #pragma unroll
        for (int T = 0; T < 7; T++) {
            const bf16x8 av = *(const bf16x8*)(w2T + (T * 16 + c16) * 416 + (ks * 4 + g) * 8);
            acc2[T] = __builtin_amdgcn_mfma_f32_16x16x32_bf16(av, bvv, acc2[T], 0, 0, 0);
        }
    }

    // ---- bias2 + LN2 (over o=98) ----
    {
        #pragma unroll
        for (int T = 0; T < 7; T++) {
            int o0 = T * 16 + g * 4;
            #pragma unroll
            for (int r = 0; r < 4; r++) {
                int o = o0 + r;
                if (o < NTOK) acc2[T][r] += bias2t[o];
            }
        }
        float S = 0.f, Q = 0.f;
        #pragma unroll
        for (int T = 0; T < 7; T++) {
            f32x4 v = acc2[T];
            S += v.x + v.y + v.z + v.w;
            Q += v.x * v.x + v.y * v.y + v.z * v.z + v.w * v.w;
        }
        S += __shfl_xor(S, 16); Q += __shfl_xor(Q, 16);
        S += __shfl_xor(S, 32); Q += __shfl_xor(Q, 32);
        float mu = S * (1.f / NTOK);
        float var = Q * (1.f / NTOK) - mu * mu;
        float rstd = rsqrtf(fmaxf(var, 0.f) + 1e-5f);
        const int swz = (c16 & 7) << 4;
        #pragma unroll
        for (int T = 0; T < 7; T++) {
            f32x4 v = acc2[T];
            uint2 u;
            if (T < 6) {
                u.x = pack2((v.x - mu) * rstd, (v.y - mu) * rstd);
                u.y = pack2((v.z - mu) * rstd, (v.w - mu) * rstd);
            } else if (g == 0) {   // o = 96,97, bias-one at o=98, zero at 99
                u.x = pack2((v.x - mu) * rstd, (v.y - mu) * rstd);
                u.y = pack2(1.0f, 0.0f);
            } else {               // o = 100..111: zeros
                u.x = 0u; u.y = 0u;
            }
            *(uint2*)(h2row + (((T * 16 + g * 4) * 2) ^ swz)) = u;
        }
        // zero k = 112..127 quads
        uint2 z; z.x = 0u; z.y = 0u;
        *(uint2*)(h2row + (((112 + g * 4) * 2) ^ swz)) = z;
    }

    // ---- GEMM3: acc3[T3][r] = H3[c = T3*16 + g*4 + r][m] ----
    f32x4 acc3[4];
    #pragma unroll
    for (int T = 0; T < 4; T++) acc3[T] = (f32x4){0.f, 0.f, 0.f, 0.f};
    {
        const int swz = (c16 & 7) << 4;
        #pragma unroll
        for (int ks = 0; ks < 4; ks++) {
            int oct = ks * 4 + g;
            const bf16x8 bvv = *(const bf16x8*)(h2row + ((oct * 16) ^ swz));
            #pragma unroll
            for (int T = 0; T < 4; T++) {
                const bf16x8 av = *(const bf16x8*)(w3T + (T * 16 + c16) * 128 + (ks * 4 + g) * 8);
                acc3[T] = __builtin_amdgcn_mfma_f32_16x16x32_bf16(av, bvv, acc3[T], 0, 0, 0);
            }
        }
    }

    // ---- LN3 (over c=49) + affine + store centroids ----
    {
        float S = 0.f, Q = 0.f;
        #pragma unroll
        for (int T = 0; T < 4; T++) {
            f32x4 v = acc3[T];
            S += v.x + v.y + v.z + v.w;
            Q += v.x * v.x + v.y * v.y + v.z * v.z + v.w * v.w;
        }
        S += __shfl_xor(S, 16); Q += __shfl_xor(Q, 16);
        S += __shfl_xor(S, 32); Q += __shfl_xor(Q, 32);
        float mu = S * (1.f / KCL);
        float var = Q * (1.f / KCL) - mu * mu;
        float rstd = rsqrtf(fmaxf(var, 0.f) + 1e-5f);
        const size_t cbase = (size_t)n * KCL * WIDTH + d0 + wv * 16 + c16;
        #pragma unroll
        for (int T = 0; T < 4; T++) {
            int c0 = T * 16 + g * 4;
            #pragma unroll
            for (int r = 0; r < 4; r++) {
                int c = c0 + r;
                if (c < KCL) {
                    float val = (acc3[T][r] - mu) * rstd * g3[c] + be3[c];
                    cent[cbase + (size_t)c * WIDTH] = val;
                }
            }
        }
    }
}

// ---------------- distances, min/argmin (unchanged fp32) ----------------
__global__ __launch_bounds__(256) void k_dist(
    const float* __restrict__ x, const float* __restrict__ cent,
    float* __restrict__ mind, int* __restrict__ assignp)
{
    int wid = blockIdx.x * 4 + (threadIdx.x >> 6);
    int lane = threadIdx.x & 63;
    int n = wid / 25, g = wid - n * 25;
    int t0 = g * 4;
    int a = n >> 6, b = n & 63;
    int bt0 = b * 12 + a * 2;

    float d[4][12];
    #pragma unroll
    for (int tt = 0; tt < 4; tt++) {
        int t = t0 + tt;
        bool valid = t < NTOK;
        int te = valid ? t : 0;
        int f = te / KCL, l = te - f * KCL;
        const float* src = x + ((size_t)(1 + l) * WIDTH + bt0 + f) * WIDTH + lane;
        #pragma unroll
        for (int i = 0; i < 12; i++) d[tt][i] = valid ? src[i * 64] : 0.f;
    }
    float nd[4];
    #pragma unroll
    for (int tt = 0; tt < 4; tt++) {
        float s = 0.f;
        #pragma unroll
        for (int i = 0; i < 12; i++) s = fmaf(d[tt][i], d[tt][i], s);
        #pragma unroll
        for (int o = 32; o > 0; o >>= 1) s += __shfl_xor(s, o);
        nd[tt] = s;
    }

    float minv[4] = {1e30f, 1e30f, 1e30f, 1e30f};
    int mini[4] = {0, 0, 0, 0};
    for (int k = 0; k < KCL; k++) {
        const float* cr = cent + ((size_t)n * KCL + k) * WIDTH + lane;
        float c[12];
        #pragma unroll
        for (int i = 0; i < 12; i++) c[i] = cr[i * 64];
        float cn = 0.f;
        #pragma unroll
        for (int i = 0; i < 12; i++) cn = fmaf(c[i], c[i], cn);
        float dot[4] = {0.f, 0.f, 0.f, 0.f};
        #pragma unroll
        for (int tt = 0; tt < 4; tt++)
            #pragma unroll
            for (int i = 0; i < 12; i++) dot[tt] = fmaf(d[tt][i], c[i], dot[tt]);
        #pragma unroll
        for (int o = 32; o > 0; o >>= 1) {
            cn += __shfl_xor(cn, o);
            #pragma unroll
            for (int tt = 0; tt < 4; tt++) dot[tt] += __shfl_xor(dot[tt], o);
        }
        #pragma unroll
        for (int tt = 0; tt < 4; tt++) {
            float dist = sqrtf(fmaxf(nd[tt] + cn - 2.f * dot[tt], 0.f));
            if (dist < minv[tt]) { minv[tt] = dist; mini[tt] = k; }
        }
    }
    if (lane == 0) {
        int nt = NTOK - t0; if (nt > 4) nt = 4;
        for (int tt = 0; tt < nt; tt++) {
            mind[n * NTOK + t0 + tt] = minv[tt];
            assignp[n * NTOK + t0 + tt] = mini[tt];
        }
    }
}

// ---------------- medoids, sort, gather, class token ----------------
__global__ __launch_bounds__(256) void k_medoid(
    const float* __restrict__ x, const float* __restrict__ mind,
    const int* __restrict__ assignp, float* __restrict__ out)
{
    __shared__ float smind[NTOK];
    __shared__ int sassign[NTOK];
    __shared__ int med[KCL], sorted[KCL];

    int n = blockIdx.x, tid = threadIdx.x;
    int a = n >> 6, b = n & 63;
    int np = b * 6 + a;
    int bt0 = b * 12 + a * 2;

    if (tid < NTOK) { smind[tid] = mind[n * NTOK + tid]; sassign[tid] = assignp[n * NTOK + tid]; }
    __syncthreads();

    if (tid < KCL) {
        float best = 1e30f; int bi = 0;
        for (int t = 0; t < NTOK; t++)
            if (sassign[t] == tid && smind[t] < best) { best = smind[t]; bi = t; }
        med[tid] = bi;
    }
    __syncthreads();
    if (tid < KCL) {
        int mk = med[tid], rank = 0;
        for (int j = 0; j < KCL; j++) {
            int mj = med[j];
            rank += (mj < mk) || (mj == mk && j < tid);
        }
        sorted[rank] = mk;
    }
    __syncthreads();

    for (int dd = tid; dd < WIDTH; dd += 256)
        out[(size_t)np * WIDTH + dd] =
            0.5f * (x[(size_t)bt0 * WIDTH + dd] + x[(size_t)(bt0 + 1) * WIDTH + dd]);

    for (int k = 0; k < KCL; k++) {
        int m = sorted[k];
        int f = m / KCL, l = m - f * KCL;
        const float* src = x + ((size_t)(1 + l) * WIDTH + bt0 + f) * WIDTH;
        float* dst = out + ((size_t)(1 + k) * NGRP + np) * WIDTH;
        for (int dd = tid; dd < WIDTH; dd += 256) dst[dd] = src[dd];
    }
}

// ---------------- loss reduction ----------------
__global__ __launch_bounds__(256) void k_loss(const float* __restrict__ mind,
                                              float* __restrict__ out_loss)
{
    __shared__ float red[256];
    float s = 0.f;
    for (int i = threadIdx.x; i < NGRP * NTOK; i += 256) s += mind[i];
    red[threadIdx.x] = s;
    __syncthreads();
    for (int o = 128; o > 0; o >>= 1) {
        if (threadIdx.x < o) red[threadIdx.x] += red[threadIdx.x + o];
        __syncthreads();
    }
    if (threadIdx.x == 0) out_loss[0] = red[0] * (1.f / NGRP);
}

extern "C" void kernel_launch(void* const* d_in, const int* in_sizes, int n_in,
                              void* d_out, int out_size, void* d_ws, size_t ws_size,
                              hipStream_t stream)
{
    const float* x   = (const float*)d_in[0];
    const float* w1  = (const float*)d_in[1];
    const float* b1  = (const float*)d_in[2];
    const float* g1  = (const float*)d_in[3];
    const float* be1 = (const float*)d_in[4];
    const float* w2  = (const float*)d_in[5];
    const float* b2  = (const float*)d_in[6];
    const float* g2  = (const float*)d_in[7];
    const float* be2 = (const float*)d_in[8];
    const float* w3  = (const float*)d_in[9];
    const float* b3  = (const float*)d_in[10];
    const float* g3  = (const float*)d_in[11];
    const float* be3 = (const float*)d_in[12];
    float* out = (float*)d_out;

    float* cent = (float*)d_ws;                                  // 384*49*768 f32
    float* mind = cent + (size_t)NGRP * KCL * WIDTH;             // 37632 f32
    int* assignp = (int*)(mind + NGRP * NTOK);                   // 37632 i32
    ushort_t* w1T = (ushort_t*)(assignp + NGRP * NTOK);          // 400*128 bf16
    ushort_t* w2T = w1T + 400 * 128;                             // 112*416 bf16
    ushort_t* w3T = w2T + 112 * 416;                             // 64*128 bf16
    float* bias2t = (float*)(w3T + 64 * 128);                    // 98 f32

    k_prep<<<4, 256, 0, stream>>>(w1, b1, g1, be1, w2, b2, g2, be2, w3, b3,
                                  w1T, w2T, w3T, bias2t);
    k_mlp<<<NGRP * 12, 256, 0, stream>>>(x, w1T, w2T, w3T, bias2t, g3, be3, cent);
    k_dist<<<(NGRP * 25) / 4, 256, 0, stream>>>(x, cent, mind, assignp);
    k_medoid<<<NGRP, 256, 0, stream>>>(x, mind, assignp, out);
    k_loss<<<1, 256, 0, stream>>>(mind, out + (out_size - 1));
}